// Round 2
// baseline (197.646 us; speedup 1.0000x reference)
//
#include <hip/hip_runtime.h>

#define C_IN   512
#define C_INT  128
#define NBUCK  1024

typedef _Float16 half8 __attribute__((ext_vector_type(8)));

// ---------- helpers ----------

__device__ __forceinline__ unsigned fkey(float f) {
    unsigned u = __float_as_uint(f);
    return (u & 0x80000000u) ? ~u : (u | 0x80000000u);
}
__device__ __forceinline__ float funkey(unsigned k) {
    unsigned u = (k & 0x80000000u) ? (k & 0x7fffffffu) : ~k;
    return __uint_as_float(u);
}
// Monotone (after clamp) bucket mapping; must be IDENTICAL in hist/scatter/out.
__device__ __forceinline__ int bucket_of(float v, float bmin, float inv_w) {
    float fk = (v - bmin) * inv_w;
    fk = fminf(fmaxf(fk, 0.f), (float)(NBUCK - 1));
    return (int)fk;
}
__device__ __forceinline__ void fma4(float4& a, float s, const float4& w) {
    a.x += s * w.x; a.y += s * w.y; a.z += s * w.z; a.w += s * w.w;
}

// ---------- K1: fused prep (ut/up/scal) + init (hist/cursor/minmax) ----------

__global__ __launch_bounds__(512) void prep_init(
        const float* __restrict__ Wt, const float* __restrict__ Wp,
        const float* __restrict__ wcat,
        const float* __restrict__ bt, const float* __restrict__ bp,
        float* __restrict__ ut, float* __restrict__ up, float* __restrict__ scal,
        unsigned* __restrict__ hist, unsigned* __restrict__ cursor,
        unsigned* __restrict__ minmax) {
    int tid = threadIdx.x;
    if (blockIdx.x == 0) {
        float su = 0.f, sp = 0.f;
        for (int c = 0; c < C_INT; ++c) {
            su += Wt[tid * C_INT + c] * wcat[c];
            sp += Wp[tid * C_INT + c] * wcat[C_INT + c];
        }
        ut[tid] = su; up[tid] = sp;
        if (tid == 0) { float s = 0.f; for (int c = 0; c < C_INT; ++c) s += bt[c] * wcat[c];        scal[0] = s; }
        if (tid == 1) { float s = 0.f; for (int c = 0; c < C_INT; ++c) s += bp[c] * wcat[C_INT + c]; scal[1] = s; }
    } else {
        int idx = (blockIdx.x - 1) * 512 + tid;
        if (idx < NBUCK)              hist[idx] = 0u;
        else if (idx < 2 * NBUCK)     cursor[idx - NBUCK] = 0u;
        else if (idx == 2 * NBUCK)    minmax[0] = 0xFFFFFFFFu;  // +inf key
        else if (idx == 2 * NBUCK + 1) minmax[1] = 0u;          // -inf key
    }
}

// ---------- K2: a[i]=x_i.ut, b[i]=x_i.up + global min/max of b ----------

__global__ __launch_bounds__(256) void ab_kernel(
        const float* __restrict__ x, const float* __restrict__ ut,
        const float* __restrict__ up, const float* __restrict__ scal,
        float* __restrict__ a, float* __restrict__ b,
        unsigned* __restrict__ minmax, int n) {
    int tid = threadIdx.x;
    int w = tid >> 6, lane = tid & 63;
    const float4* ut4 = (const float4*)ut;
    const float4* up4 = (const float4*)up;
    float4 u0 = ut4[lane], u1 = ut4[64 + lane];
    float4 p0 = up4[lane], p1 = up4[64 + lane];
    float aoff = scal[0], boff = scal[1];
    float bmn = 1e30f, bmx = -1e30f;
    int row0 = blockIdx.x * 16 + w * 4;
    for (int rr = 0; rr < 4; ++rr) {
        int row = row0 + rr;
        if (row >= n) break;
        const float4* xr = (const float4*)(x + (size_t)row * C_IN);
        float4 x0 = xr[lane], x1 = xr[64 + lane];
        float sa = x0.x*u0.x + x0.y*u0.y + x0.z*u0.z + x0.w*u0.w
                 + x1.x*u1.x + x1.y*u1.y + x1.z*u1.z + x1.w*u1.w;
        float sb = x0.x*p0.x + x0.y*p0.y + x0.z*p0.z + x0.w*p0.w
                 + x1.x*p1.x + x1.y*p1.y + x1.z*p1.z + x1.w*p1.w;
        for (int off = 32; off; off >>= 1) {
            sa += __shfl_down(sa, off);
            sb += __shfl_down(sb, off);
        }
        if (lane == 0) {
            sa += aoff; sb += boff;
            a[row] = sa; b[row] = sb;
            bmn = fminf(bmn, sb); bmx = fmaxf(bmx, sb);
        }
    }
    __shared__ unsigned smn, smx;
    if (tid == 0) { smn = 0xFFFFFFFFu; smx = 0u; }
    __syncthreads();
    if (lane == 0) { atomicMin(&smn, fkey(bmn)); atomicMax(&smx, fkey(bmx)); }
    __syncthreads();
    if (tid == 0) { atomicMin(&minmax[0], smn); atomicMax(&minmax[1], smx); }
}

// ---------- K3: g = x @ Wg + bg  -> fp16 (tiled fp32 GEMM, 32 rows x 128 cols / block) ----------

__global__ __launch_bounds__(256) void gemm_g(
        const float* __restrict__ x, const float* __restrict__ Wg,
        const float* __restrict__ bg, _Float16* __restrict__ g) {
    __shared__ float xs[32][36];
    __shared__ float wsh[32][128];
    int tid = threadIdx.x;
    int brow = blockIdx.x * 32;
    int tc = tid & 15, tr = tid >> 4;
    float4 acc00 = {0,0,0,0}, acc01 = {0,0,0,0};
    float4 acc10 = {0,0,0,0}, acc11 = {0,0,0,0};
    int xr = tid >> 3, xc4 = tid & 7;
    const float4* Wg4 = (const float4*)Wg;
    float4* wsh4 = (float4*)&wsh[0][0];
    for (int kc = 0; kc < C_IN; kc += 32) {
        float4 xv = *(const float4*)(x + (size_t)(brow + xr) * C_IN + kc + xc4 * 4);
        *(float4*)(&xs[xr][xc4 * 4]) = xv;
        #pragma unroll
        for (int t = 0; t < 4; ++t)
            wsh4[t * 256 + tid] = Wg4[kc * 32 + t * 256 + tid];
        __syncthreads();
        #pragma unroll
        for (int kk = 0; kk < 32; ++kk) {
            float x0 = xs[tr * 2 + 0][kk];
            float x1 = xs[tr * 2 + 1][kk];
            float4 w0 = *(float4*)(&wsh[kk][tc * 8]);
            float4 w1 = *(float4*)(&wsh[kk][tc * 8 + 4]);
            fma4(acc00, x0, w0); fma4(acc01, x0, w1);
            fma4(acc10, x1, w0); fma4(acc11, x1, w1);
        }
        __syncthreads();
    }
    float4 b0 = *(const float4*)(bg + tc * 8);
    float4 b1 = *(const float4*)(bg + tc * 8 + 4);
    int r0 = brow + tr * 2;
    half8 h0, h1;
    h0[0] = (_Float16)(acc00.x + b0.x); h0[1] = (_Float16)(acc00.y + b0.y);
    h0[2] = (_Float16)(acc00.z + b0.z); h0[3] = (_Float16)(acc00.w + b0.w);
    h0[4] = (_Float16)(acc01.x + b1.x); h0[5] = (_Float16)(acc01.y + b1.y);
    h0[6] = (_Float16)(acc01.z + b1.z); h0[7] = (_Float16)(acc01.w + b1.w);
    h1[0] = (_Float16)(acc10.x + b0.x); h1[1] = (_Float16)(acc10.y + b0.y);
    h1[2] = (_Float16)(acc10.z + b0.z); h1[3] = (_Float16)(acc10.w + b0.w);
    h1[4] = (_Float16)(acc11.x + b1.x); h1[5] = (_Float16)(acc11.y + b1.y);
    h1[6] = (_Float16)(acc11.z + b1.z); h1[7] = (_Float16)(acc11.w + b1.w);
    *(half8*)(g + (size_t)r0 * C_INT + tc * 8)       = h0;
    *(half8*)(g + (size_t)(r0 + 1) * C_INT + tc * 8) = h1;
}

// ---------- K4: histogram of b ----------

__global__ __launch_bounds__(256) void hist_kernel(
        const float* __restrict__ b, const unsigned* __restrict__ minmax,
        unsigned* __restrict__ hist, int n) {
    int j = blockIdx.x * 256 + threadIdx.x;
    if (j >= n) return;
    float bmin = funkey(minmax[0]), bmax = funkey(minmax[1]);
    float range = bmax - bmin;
    float inv_w = range > 0.f ? (float)NBUCK / range : 0.f;
    atomicAdd(&hist[bucket_of(b[j], bmin, inv_w)], 1u);
}

// ---------- K5: exclusive scan of hist (single block) ----------

__global__ __launch_bounds__(1024) void scan_hist(
        const unsigned* __restrict__ hist, unsigned* __restrict__ offs) {
    __shared__ unsigned s[2][NBUCK];
    int t = threadIdx.x;
    unsigned v = hist[t];
    s[0][t] = v; __syncthreads();
    int pp = 0;
    for (int d = 1; d < NBUCK; d <<= 1) {
        unsigned val = s[pp][t];
        if (t >= d) val += s[pp][t - d];
        s[1 - pp][t] = val; pp ^= 1; __syncthreads();
    }
    unsigned incl = s[pp][t];
    offs[t] = incl - v;
    if (t == NBUCK - 1) offs[NBUCK] = incl;
}

// ---------- K6: scatter row indices into bucket lists ----------

__global__ __launch_bounds__(256) void scatter_kernel(
        const float* __restrict__ b, const unsigned* __restrict__ minmax,
        const unsigned* __restrict__ offs, unsigned* __restrict__ cursor,
        unsigned* __restrict__ list, int n) {
    int j = blockIdx.x * 256 + threadIdx.x;
    if (j >= n) return;
    float bmin = funkey(minmax[0]), bmax = funkey(minmax[1]);
    float range = bmax - bmin;
    float inv_w = range > 0.f ? (float)NBUCK / range : 0.f;
    int k = bucket_of(b[j], bmin, inv_w);
    unsigned pos = atomicAdd(&cursor[k], 1u);
    list[offs[k] + pos] = (unsigned)j;
}

// ---------- K7: per-bucket sums written straight into P1/P2 rows 0..NBUCK-1 ----------

__global__ __launch_bounds__(128) void bucketsum_kernel(
        const _Float16* __restrict__ g, const float* __restrict__ b,
        const unsigned* __restrict__ offs, const unsigned* __restrict__ list,
        float* __restrict__ P1, float* __restrict__ P2) {
    int k = blockIdx.x, c = threadIdx.x;
    float h1 = 0.f, h2 = 0.f;
    unsigned e0 = offs[k], e1 = offs[k + 1];
    for (unsigned e = e0; e < e1; ++e) {
        unsigned j = list[e];
        float bj = b[j];
        float gv = (float)g[(size_t)j * C_INT + c];
        h1 += gv; h2 += bj * gv;
    }
    P1[(size_t)k * C_INT + c] = h1;
    P2[(size_t)k * C_INT + c] = h2;
}

// ---------- K8: in-place suffix sums over buckets (per channel) ----------

__global__ __launch_bounds__(1024) void suffix_scan(
        float* __restrict__ P1, float* __restrict__ P2) {
    __shared__ float s[2][NBUCK];
    int c = blockIdx.x, t = threadIdx.x;
    for (int pass = 0; pass < 2; ++pass) {
        float* P = pass ? P2 : P1;
        float v = P[(size_t)t * C_INT + c];
        s[0][t] = v; __syncthreads();
        int pp = 0;
        for (int d = 1; d < NBUCK; d <<= 1) {
            float val = s[pp][t];
            if (t >= d) val += s[pp][t - d];
            s[1 - pp][t] = val; pp ^= 1; __syncthreads();
        }
        float incl = s[pp][t];
        float total = s[pp][NBUCK - 1];
        P[(size_t)t * C_INT + c] = total - incl + v;   // sum_{t' >= t}
        if (t == 0) P[(size_t)NBUCK * C_INT + c] = 0.f;
        __syncthreads();
    }
}

// ---------- K9: per-row output ----------

__global__ __launch_bounds__(128) void out_kernel(
        const float* __restrict__ a, const float* __restrict__ b,
        const _Float16* __restrict__ g, const unsigned* __restrict__ minmax,
        const unsigned* __restrict__ offs, const unsigned* __restrict__ list,
        const float* __restrict__ P1, const float* __restrict__ P2,
        float* __restrict__ out, int n, float inv_n) {
    int i = blockIdx.x, c = threadIdx.x;
    float ai = a[i];
    float t = -ai;
    float bmin = funkey(minmax[0]), bmax = funkey(minmax[1]);
    float range = bmax - bmin;
    float inv_w = range > 0.f ? (float)NBUCK / range : 0.f;
    int ki = bucket_of(t, bmin, inv_w);
    size_t base = (size_t)(ki + 1) * C_INT;
    float acc = ai * P1[base + c] + P2[base + c];
    unsigned e0 = offs[ki], e1 = offs[ki + 1];
    for (unsigned e = e0; e < e1; ++e) {
        unsigned j = list[e];
        float bj = b[j];
        if (bj > t) acc += (ai + bj) * (float)g[(size_t)j * C_INT + c];
    }
    out[(size_t)i * C_INT + c] = acc * inv_n;
}

// ---------- launch ----------

extern "C" void kernel_launch(void* const* d_in, const int* in_sizes, int n_in,
                              void* d_out, int out_size, void* d_ws, size_t ws_size,
                              hipStream_t stream) {
    const float* x    = (const float*)d_in[0];
    const float* Wg   = (const float*)d_in[1];
    const float* bg   = (const float*)d_in[2];
    const float* Wt   = (const float*)d_in[3];
    const float* bt   = (const float*)d_in[4];
    const float* Wp   = (const float*)d_in[5];
    const float* bp   = (const float*)d_in[6];
    const float* wcat = (const float*)d_in[7];
    float* out = (float*)d_out;
    int n = in_sizes[0] / C_IN;   // 8192

    char* w = (char*)d_ws;
    size_t off = 0;
    auto alloc = [&](size_t bytes) -> void* {
        void* p = w + off;
        off += (bytes + 255) & ~(size_t)255;
        return p;
    };
    // Total footprint ~3.12 MB (previous 6.2 MB overflowed ws -> replay corruption).
    float*    ut     = (float*)alloc(C_IN * 4);
    float*    up     = (float*)alloc(C_IN * 4);
    float*    scal   = (float*)alloc(16);
    float*    a      = (float*)alloc((size_t)n * 4);
    float*    b      = (float*)alloc((size_t)n * 4);
    unsigned* minmax = (unsigned*)alloc(16);
    unsigned* hist   = (unsigned*)alloc(NBUCK * 4);
    unsigned* offs   = (unsigned*)alloc((NBUCK + 1) * 4);
    unsigned* cursor = (unsigned*)alloc(NBUCK * 4);
    unsigned* list   = (unsigned*)alloc((size_t)n * 4);
    _Float16* g      = (_Float16*)alloc((size_t)n * C_INT * 2);
    float*    P1     = (float*)alloc((size_t)(NBUCK + 1) * C_INT * 4);
    float*    P2     = (float*)alloc((size_t)(NBUCK + 1) * C_INT * 4);

    int init_blocks = 1 + (2 * NBUCK + 2 + 511) / 512;
    prep_init<<<init_blocks, 512, 0, stream>>>(Wt, Wp, wcat, bt, bp, ut, up, scal,
                                               hist, cursor, minmax);
    ab_kernel<<<(n + 15) / 16, 256, 0, stream>>>(x, ut, up, scal, a, b, minmax, n);
    gemm_g<<<n / 32, 256, 0, stream>>>(x, Wg, bg, g);
    hist_kernel<<<(n + 255) / 256, 256, 0, stream>>>(b, minmax, hist, n);
    scan_hist<<<1, NBUCK, 0, stream>>>(hist, offs);
    scatter_kernel<<<(n + 255) / 256, 256, 0, stream>>>(b, minmax, offs, cursor, list, n);
    bucketsum_kernel<<<NBUCK, C_INT, 0, stream>>>(g, b, offs, list, P1, P2);
    suffix_scan<<<C_INT, NBUCK, 0, stream>>>(P1, P2);
    out_kernel<<<n, C_INT, 0, stream>>>(a, b, g, minmax, offs, list, P1, P2,
                                        out, n, 1.0f / (float)n);
}

// Round 4
// 183.656 us; speedup vs baseline: 1.0762x; 1.0762x over previous
//
#include <hip/hip_runtime.h>

#define C_IN    512
#define C_INT   128
#define NBUCK   1024
#define NMAX    8192

typedef _Float16 half8 __attribute__((ext_vector_type(8)));

// ---------- helpers ----------

// Monotone (after clamp) bucket mapping; identical everywhere it is used.
__device__ __forceinline__ int bucket_of(float v, float bmin, float inv_w) {
    float fk = (v - bmin) * inv_w;
    fk = fminf(fmaxf(fk, 0.f), (float)(NBUCK - 1));
    return (int)fk;
}
__device__ __forceinline__ void fma4(float4& a, float s, const float4& w) {
    a.x += s * w.x; a.y += s * w.y; a.z += s * w.z; a.w += s * w.w;
}

// ---------- K1: prep ----------
// blocks 0..7: ut (64 rows each); 8..15: up; 16: scal = {s0, s1, bmin, inv_w}
// b ~ N(s1, ||up||^2) exactly (x ~ N(0,I)), so bucket range = s1 +- 8*sigma.

__global__ __launch_bounds__(256) void prep_kernel(
        const float* __restrict__ Wt, const float* __restrict__ Wp,
        const float* __restrict__ wcat,
        const float* __restrict__ bt, const float* __restrict__ bp,
        float* __restrict__ ut, float* __restrict__ up, float* __restrict__ scal) {
    int t = threadIdx.x, bk = blockIdx.x;
    if (bk < 16) {
        const float* W  = (bk < 8) ? Wt : Wp;
        const float* wv = wcat + ((bk < 8) ? 0 : C_INT);
        float* dst      = (bk < 8) ? ut : up;
        int k = (bk & 7) * 64 + (t >> 2);   // 64 k per block
        int q = t & 3;                       // 4 lanes per k
        const float4* row = (const float4*)(W + (size_t)k * C_INT);
        const float4* cv4 = (const float4*)wv;
        float s = 0.f;
        #pragma unroll
        for (int i = 0; i < 8; ++i) {
            float4 a = row[q * 8 + i];
            float4 c = cv4[q * 8 + i];
            s += a.x * c.x + a.y * c.y + a.z * c.z + a.w * c.w;
        }
        s += __shfl_xor(s, 1);
        s += __shfl_xor(s, 2);
        if (q == 0) dst[k] = s;
    } else {
        // sigma: redundantly recompute up rows (2 per thread) and sum squares
        float sumsq = 0.f;
        const float4* w2v = (const float4*)(wcat + C_INT);
        for (int r = 0; r < 2; ++r) {
            int k = t * 2 + r;
            const float4* row = (const float4*)(Wp + (size_t)k * C_INT);
            float d = 0.f;
            #pragma unroll
            for (int i = 0; i < 32; ++i) {
                float4 a4 = row[i]; float4 c4 = w2v[i];
                d += a4.x * c4.x + a4.y * c4.y + a4.z * c4.z + a4.w * c4.w;
            }
            sumsq += d * d;
        }
        float s1p = (t < C_INT) ? bt[t] * wcat[t] : 0.f;
        float s2p = (t < C_INT) ? bp[t] * wcat[C_INT + t] : 0.f;
        for (int off = 32; off; off >>= 1) {
            s1p   += __shfl_down(s1p, off);
            s2p   += __shfl_down(s2p, off);
            sumsq += __shfl_down(sumsq, off);
        }
        __shared__ float red[12];
        int w = t >> 6, lane = t & 63;
        if (lane == 0) { red[w] = s1p; red[4 + w] = s2p; red[8 + w] = sumsq; }
        __syncthreads();
        if (t == 0) {
            float s0 = red[0] + red[1] + red[2] + red[3];
            float s1 = red[4] + red[5] + red[6] + red[7];
            float sq = red[8] + red[9] + red[10] + red[11];
            float sigma = sqrtf(sq);
            scal[0] = s0; scal[1] = s1;
            if (sigma > 1e-20f) {
                scal[2] = s1 - 8.f * sigma;                  // bmin
                scal[3] = (float)NBUCK / (16.f * sigma);     // inv_w
            } else {
                scal[2] = s1 - 1.f; scal[3] = 0.f;           // degenerate: all bucket 0
            }
        }
    }
}

// ---------- K2: fused g = x@Wg+bg (fp16 out), a = x.ut+s0, b = x.up+s1 ----------
// 16 rows x 128 cols per block; x read exactly once.

__global__ __launch_bounds__(256) void gemmab_kernel(
        const float* __restrict__ x, const float* __restrict__ Wg,
        const float* __restrict__ bg,
        const float* __restrict__ ut, const float* __restrict__ up,
        const float* __restrict__ scal,
        _Float16* __restrict__ g, float* __restrict__ a, float* __restrict__ b,
        int n) {
    __shared__ float xs[16][36];
    __shared__ float wsh[32][128];
    __shared__ float uts[C_IN], ups[C_IN];
    int tid = threadIdx.x;
    int brow = blockIdx.x * 16;
    for (int i = tid; i < C_IN; i += 256) { uts[i] = ut[i]; ups[i] = up[i]; }
    int tr = tid >> 4, tc = tid & 15;
    float4 acc0 = {0,0,0,0}, acc1 = {0,0,0,0};
    float sa = 0.f, sb = 0.f;
    const float4* Wg4 = (const float4*)Wg;
    float4* wsh4 = (float4*)&wsh[0][0];
    int xr = tid >> 3, xc4 = tid & 7;
    __syncthreads();
    for (int kc = 0; kc < C_IN; kc += 32) {
        if (tid < 128) {
            float4 xv = *(const float4*)(x + (size_t)(brow + xr) * C_IN + kc + xc4 * 4);
            *(float4*)(&xs[xr][xc4 * 4]) = xv;
        }
        #pragma unroll
        for (int t2 = 0; t2 < 4; ++t2)
            wsh4[t2 * 256 + tid] = Wg4[kc * 32 + t2 * 256 + tid];
        __syncthreads();
        #pragma unroll
        for (int kk = 0; kk < 32; ++kk) {
            float x0 = xs[tr][kk];
            float4 w0 = *(float4*)(&wsh[kk][tc * 8]);
            float4 w1 = *(float4*)(&wsh[kk][tc * 8 + 4]);
            fma4(acc0, x0, w0); fma4(acc1, x0, w1);
        }
        float xa0 = xs[tr][tc * 2], xa1 = xs[tr][tc * 2 + 1];
        sa += xa0 * uts[kc + tc * 2] + xa1 * uts[kc + tc * 2 + 1];
        sb += xa0 * ups[kc + tc * 2] + xa1 * ups[kc + tc * 2 + 1];
        __syncthreads();
    }
    float4 b0 = *(const float4*)(bg + tc * 8);
    float4 b1 = *(const float4*)(bg + tc * 8 + 4);
    half8 h;
    h[0] = (_Float16)(acc0.x + b0.x); h[1] = (_Float16)(acc0.y + b0.y);
    h[2] = (_Float16)(acc0.z + b0.z); h[3] = (_Float16)(acc0.w + b0.w);
    h[4] = (_Float16)(acc1.x + b1.x); h[5] = (_Float16)(acc1.y + b1.y);
    h[6] = (_Float16)(acc1.z + b1.z); h[7] = (_Float16)(acc1.w + b1.w);
    *(half8*)(g + (size_t)(brow + tr) * C_INT + tc * 8) = h;
    sa += __shfl_xor(sa, 1); sb += __shfl_xor(sb, 1);
    sa += __shfl_xor(sa, 2); sb += __shfl_xor(sb, 2);
    sa += __shfl_xor(sa, 4); sb += __shfl_xor(sb, 4);
    sa += __shfl_xor(sa, 8); sb += __shfl_xor(sb, 8);
    if (tc == 0) {
        a[brow + tr] = sa + scal[0];
        b[brow + tr] = sb + scal[1];
    }
}

// ---------- K3: self-sorting bucketsum + suffix scan, one block per channel ----------
// Each block: load b -> LDS, hist -> scan -> scatter (u16 list) in LDS,
// bucket sums for its channel, suffix scan, write P1/P2.
// Block 0 additionally publishes offs + list to global for out_kernel.

__global__ __launch_bounds__(1024) void bucketsuffix_kernel(
        const _Float16* __restrict__ g, const float* __restrict__ b,
        const float* __restrict__ scal,
        unsigned* __restrict__ offs_g, unsigned* __restrict__ list_g,
        float* __restrict__ P1, float* __restrict__ P2, int n) {
    __shared__ float bl[NMAX];
    __shared__ unsigned short ls[NMAX];
    __shared__ unsigned oh[NBUCK];      // hist -> inclusive scan
    __shared__ unsigned cur[NBUCK];
    __shared__ float sc1[NBUCK], sc2[NBUCK];
    int t = threadIdx.x, c = blockIdx.x;
    float bmin = scal[2], inv_w = scal[3];
    for (int j = t; j < n; j += 1024) bl[j] = b[j];
    oh[t] = 0u; cur[t] = 0u;
    __syncthreads();
    // histogram
    for (int j = t; j < n; j += 1024)
        atomicAdd(&oh[bucket_of(bl[j], bmin, inv_w)], 1u);
    __syncthreads();
    // inclusive Hillis-Steele scan of oh
    for (int d = 1; d < NBUCK; d <<= 1) {
        unsigned v = oh[t];
        if (t >= d) v += oh[t - d];
        __syncthreads();
        oh[t] = v;
        __syncthreads();
    }
    // scatter: exclusive offset of bucket k = (k ? oh[k-1] : 0)
    for (int j = t; j < n; j += 1024) {
        int k = bucket_of(bl[j], bmin, inv_w);
        unsigned e0 = (k > 0) ? oh[k - 1] : 0u;
        unsigned pos = atomicAdd(&cur[k], 1u);
        ls[e0 + pos] = (unsigned short)j;
    }
    __syncthreads();
    if (c == 0) {
        for (int j = t; j < n; j += 1024) list_g[j] = (unsigned)ls[j];
        offs_g[t + 1] = oh[t];
        if (t == 0) offs_g[0] = 0u;
    }
    // bucket sums for channel c (thread t = bucket t)
    unsigned e0 = (t > 0) ? oh[t - 1] : 0u, e1 = oh[t];
    float h1 = 0.f, h2 = 0.f;
    for (unsigned e = e0; e < e1; ++e) {
        int j = ls[e];
        float bj = bl[j];
        float gv = (float)g[(size_t)j * C_INT + c];
        h1 += gv; h2 += bj * gv;
    }
    sc1[t] = h1; sc2[t] = h2;
    __syncthreads();
    // inclusive scans for both sums
    for (int d = 1; d < NBUCK; d <<= 1) {
        float v1 = sc1[t], v2 = sc2[t];
        if (t >= d) { v1 += sc1[t - d]; v2 += sc2[t - d]; }
        __syncthreads();
        sc1[t] = v1; sc2[t] = v2;
        __syncthreads();
    }
    float tot1 = sc1[NBUCK - 1], tot2 = sc2[NBUCK - 1];
    P1[(size_t)t * C_INT + c] = tot1 - sc1[t] + h1;   // sum over buckets >= t
    P2[(size_t)t * C_INT + c] = tot2 - sc2[t] + h2;
    if (t == 0) {
        P1[(size_t)NBUCK * C_INT + c] = 0.f;
        P2[(size_t)NBUCK * C_INT + c] = 0.f;
    }
}

// ---------- K4: per-row output ----------

__global__ __launch_bounds__(128) void out_kernel(
        const float* __restrict__ a, const float* __restrict__ b,
        const _Float16* __restrict__ g, const float* __restrict__ scal,
        const unsigned* __restrict__ offs, const unsigned* __restrict__ list,
        const float* __restrict__ P1, const float* __restrict__ P2,
        float* __restrict__ out, int n, float inv_n) {
    int i = blockIdx.x, c = threadIdx.x;
    float ai = a[i], thr = -ai;
    float bmin = scal[2], inv_w = scal[3];
    int ki = bucket_of(thr, bmin, inv_w);
    size_t base = (size_t)(ki + 1) * C_INT;
    float acc = ai * P1[base + c] + P2[base + c];
    unsigned e0 = offs[ki], e1 = offs[ki + 1];
    for (unsigned e = e0; e < e1; ++e) {
        unsigned j = list[e];
        float bj = b[j];
        if (bj > thr) acc += (ai + bj) * (float)g[(size_t)j * C_INT + c];
    }
    out[(size_t)i * C_INT + c] = acc * inv_n;
}

// ---------- launch ----------

extern "C" void kernel_launch(void* const* d_in, const int* in_sizes, int n_in,
                              void* d_out, int out_size, void* d_ws, size_t ws_size,
                              hipStream_t stream) {
    const float* x    = (const float*)d_in[0];
    const float* Wg   = (const float*)d_in[1];
    const float* bg   = (const float*)d_in[2];
    const float* Wt   = (const float*)d_in[3];
    const float* bt   = (const float*)d_in[4];
    const float* Wp   = (const float*)d_in[5];
    const float* bp   = (const float*)d_in[6];
    const float* wcat = (const float*)d_in[7];
    float* out = (float*)d_out;
    int n = in_sizes[0] / C_IN;   // 8192

    char* w = (char*)d_ws;
    size_t off = 0;
    auto alloc = [&](size_t bytes) -> void* {
        void* p = w + off;
        off += (bytes + 255) & ~(size_t)255;
        return p;
    };
    float*    ut   = (float*)alloc(C_IN * 4);
    float*    up   = (float*)alloc(C_IN * 4);
    float*    scal = (float*)alloc(16);
    float*    a    = (float*)alloc((size_t)n * 4);
    float*    b    = (float*)alloc((size_t)n * 4);
    unsigned* offs = (unsigned*)alloc((NBUCK + 1) * 4);
    unsigned* list = (unsigned*)alloc((size_t)n * 4);
    _Float16* g    = (_Float16*)alloc((size_t)n * C_INT * 2);
    float*    P1   = (float*)alloc((size_t)(NBUCK + 1) * C_INT * 4);
    float*    P2   = (float*)alloc((size_t)(NBUCK + 1) * C_INT * 4);

    prep_kernel<<<17, 256, 0, stream>>>(Wt, Wp, wcat, bt, bp, ut, up, scal);
    gemmab_kernel<<<n / 16, 256, 0, stream>>>(x, Wg, bg, ut, up, scal, g, a, b, n);
    bucketsuffix_kernel<<<C_INT, 1024, 0, stream>>>(g, b, scal, offs, list, P1, P2, n);
    out_kernel<<<n, C_INT, 0, stream>>>(a, b, g, scal, offs, list, P1, P2,
                                        out, n, 1.0f / (float)n);
}

// Round 5
// 160.980 us; speedup vs baseline: 1.2278x; 1.1409x over previous
//
#include <hip/hip_runtime.h>

#define C_IN   512
#define C_INT  128
#define NBUCK  1024
#define NMAX   8192

typedef _Float16 half8 __attribute__((ext_vector_type(8)));
typedef short short8 __attribute__((ext_vector_type(8)));
typedef float floatx4 __attribute__((ext_vector_type(4)));

// ---------- helpers ----------

// Monotone (after clamp) bucket mapping; identical everywhere it is used.
__device__ __forceinline__ int bucket_of(float v, float bmin, float inv_w) {
    float fk = (v - bmin) * inv_w;
    fk = fminf(fmaxf(fk, 0.f), (float)(NBUCK - 1));
    return (int)fk;
}

// fp32 -> bf16 round-to-nearest-even
__device__ __forceinline__ short bf16rnd(float v) {
    unsigned u = __float_as_uint(v);
    return (short)((u + 0x7fffu + ((u >> 16) & 1u)) >> 16);
}

// ---------- K1: prep ----------
// blocks 0..7: ut (64 rows each); 8..15: up; 16: scal = {s0, s1, bmin, inv_w};
// 17..24: Wg (512x128 fp32) -> WgT (128x512 bf16) transpose+convert.
// b ~ N(s1, ||up||^2) exactly (x ~ N(0,I)), so bucket range = s1 +- 8*sigma.

__global__ __launch_bounds__(256) void prep_kernel(
        const float* __restrict__ Wt, const float* __restrict__ Wp,
        const float* __restrict__ Wg, const float* __restrict__ wcat,
        const float* __restrict__ bt, const float* __restrict__ bp,
        float* __restrict__ ut, float* __restrict__ up, float* __restrict__ scal,
        unsigned short* __restrict__ WgT) {
    int t = threadIdx.x, bk = blockIdx.x;
    if (bk < 16) {
        const float* W  = (bk < 8) ? Wt : Wp;
        const float* wv = wcat + ((bk < 8) ? 0 : C_INT);
        float* dst      = (bk < 8) ? ut : up;
        int k = (bk & 7) * 64 + (t >> 2);   // 64 k per block
        int q = t & 3;                       // 4 lanes per k
        const float4* row = (const float4*)(W + (size_t)k * C_INT);
        const float4* cv4 = (const float4*)wv;
        float s = 0.f;
        #pragma unroll
        for (int i = 0; i < 8; ++i) {
            float4 a = row[q * 8 + i];
            float4 c = cv4[q * 8 + i];
            s += a.x * c.x + a.y * c.y + a.z * c.z + a.w * c.w;
        }
        s += __shfl_xor(s, 1);
        s += __shfl_xor(s, 2);
        if (q == 0) dst[k] = s;
    } else if (bk == 16) {
        // sigma: redundantly recompute up rows (2 per thread) and sum squares
        float sumsq = 0.f;
        const float4* w2v = (const float4*)(wcat + C_INT);
        for (int r = 0; r < 2; ++r) {
            int k = t * 2 + r;
            const float4* row = (const float4*)(Wp + (size_t)k * C_INT);
            float d = 0.f;
            #pragma unroll
            for (int i = 0; i < 32; ++i) {
                float4 a4 = row[i]; float4 c4 = w2v[i];
                d += a4.x * c4.x + a4.y * c4.y + a4.z * c4.z + a4.w * c4.w;
            }
            sumsq += d * d;
        }
        float s1p = (t < C_INT) ? bt[t] * wcat[t] : 0.f;
        float s2p = (t < C_INT) ? bp[t] * wcat[C_INT + t] : 0.f;
        for (int off = 32; off; off >>= 1) {
            s1p   += __shfl_down(s1p, off);
            s2p   += __shfl_down(s2p, off);
            sumsq += __shfl_down(sumsq, off);
        }
        __shared__ float red[12];
        int w = t >> 6, lane = t & 63;
        if (lane == 0) { red[w] = s1p; red[4 + w] = s2p; red[8 + w] = sumsq; }
        __syncthreads();
        if (t == 0) {
            float s0 = red[0] + red[1] + red[2] + red[3];
            float s1 = red[4] + red[5] + red[6] + red[7];
            float sq = red[8] + red[9] + red[10] + red[11];
            float sigma = sqrtf(sq);
            scal[0] = s0; scal[1] = s1;
            if (sigma > 1e-20f) {
                scal[2] = s1 - 8.f * sigma;                  // bmin
                scal[3] = (float)NBUCK / (16.f * sigma);     // inv_w
            } else {
                scal[2] = s1 - 1.f; scal[3] = 0.f;           // degenerate: all bucket 0
            }
        }
    } else {
        // transpose+convert one 64-row k-slice of Wg
        __shared__ float tile[64][132];
        int kb = (bk - 17) * 64;
        #pragma unroll
        for (int it = 0; it < 8; ++it) {
            int idx = it * 256 + t;          // 2048 float4 = 64x128 floats
            int r = idx >> 5, c4 = idx & 31;
            *(float4*)&tile[r][c4 * 4] =
                ((const float4*)(Wg + (size_t)(kb + r) * C_INT))[c4];
        }
        __syncthreads();
        int n = t & 127, kc = (t >> 7) * 32;  // 128 n x 2 k-chunks
        unsigned pk[16];
        #pragma unroll
        for (int i = 0; i < 16; ++i) {
            unsigned lo = (unsigned short)bf16rnd(tile[kc + 2 * i][n]);
            unsigned hi = (unsigned short)bf16rnd(tile[kc + 2 * i + 1][n]);
            pk[i] = lo | (hi << 16);
        }
        uint4* dst = (uint4*)(WgT + (size_t)n * C_IN + kb + kc);
        #pragma unroll
        for (int i2 = 0; i2 < 4; ++i2) dst[i2] = *(uint4*)&pk[i2 * 4];
    }
}

// ---------- K2: MFMA gemm, barrier-free / LDS-free ----------
// 1 wave per block, 16 rows per wave, all 128 g-cols + [a|b] cols.
// A-frags straight from global x (fp32 -> bf16 in regs); B-frags straight
// from L2-resident WgT (bf16). 9 mfma per K-step, 16 steps.

__global__ __launch_bounds__(64) void gemm_mfma(
        const float* __restrict__ x, const unsigned short* __restrict__ WgT,
        const float* __restrict__ bg,
        const float* __restrict__ ut, const float* __restrict__ up,
        const float* __restrict__ scal,
        _Float16* __restrict__ g, float* __restrict__ a, float* __restrict__ b) {
    int lane = threadIdx.x;
    int i0 = blockIdx.x * 16;
    int m = lane & 15, q = lane >> 4;
    floatx4 accg[8] = {};
    floatx4 accab = {};
    const float* xrow = x + (size_t)(i0 + m) * C_IN + q * 8;
    const float* absrc = (m == 0) ? ut : up;   // used only when m < 2
    #pragma unroll
    for (int ks = 0; ks < 16; ++ks) {
        int k0 = ks * 32;
        float4 f0 = *(const float4*)(xrow + k0);
        float4 f1 = *(const float4*)(xrow + k0 + 4);
        short8 af;
        af[0] = bf16rnd(f0.x); af[1] = bf16rnd(f0.y);
        af[2] = bf16rnd(f0.z); af[3] = bf16rnd(f0.w);
        af[4] = bf16rnd(f1.x); af[5] = bf16rnd(f1.y);
        af[6] = bf16rnd(f1.z); af[7] = bf16rnd(f1.w);
        short8 abf = {};
        if (m < 2) {
            float4 u0 = *(const float4*)(absrc + k0 + q * 8);
            float4 u1 = *(const float4*)(absrc + k0 + q * 8 + 4);
            abf[0] = bf16rnd(u0.x); abf[1] = bf16rnd(u0.y);
            abf[2] = bf16rnd(u0.z); abf[3] = bf16rnd(u0.w);
            abf[4] = bf16rnd(u1.x); abf[5] = bf16rnd(u1.y);
            abf[6] = bf16rnd(u1.z); abf[7] = bf16rnd(u1.w);
        }
        accab = __builtin_amdgcn_mfma_f32_16x16x32_bf16(af, abf, accab, 0, 0, 0);
        #pragma unroll
        for (int f = 0; f < 8; ++f) {
            short8 bfr = *(const short8*)(WgT + (size_t)(f * 16 + m) * C_IN + k0 + q * 8);
            accg[f] = __builtin_amdgcn_mfma_f32_16x16x32_bf16(af, bfr, accg[f], 0, 0, 0);
        }
    }
    // epilogue: C layout col = lane&15, row = q*4 + reg
    #pragma unroll
    for (int f = 0; f < 8; ++f) {
        int col = f * 16 + m;
        float bgv = bg[col];
        #pragma unroll
        for (int r = 0; r < 4; ++r) {
            int row = i0 + q * 4 + r;
            g[(size_t)row * C_INT + col] = (_Float16)(accg[f][r] + bgv);
        }
    }
    if (m < 2) {
        float off = m ? scal[1] : scal[0];
        float* dst = m ? b : a;
        #pragma unroll
        for (int r = 0; r < 4; ++r) dst[i0 + q * 4 + r] = accab[r] + off;
    }
}

// ---------- K3: self-sorting bucketsum + suffix scan (shfl scans), 1 block/channel ----------

__global__ __launch_bounds__(1024) void bucketsuffix_kernel(
        const _Float16* __restrict__ g, const float* __restrict__ b,
        const float* __restrict__ scal,
        unsigned* __restrict__ offs_g, unsigned* __restrict__ list_g,
        float* __restrict__ P1, float* __restrict__ P2, int n) {
    __shared__ float bl[NMAX];
    __shared__ unsigned short ls[NMAX];
    __shared__ unsigned oh[NBUCK];
    __shared__ unsigned cur[NBUCK];
    __shared__ unsigned wtu[16];
    __shared__ float wt1[16], wt2[16];
    int t = threadIdx.x, c = blockIdx.x;
    int lane = t & 63, wv = t >> 6;
    float bmin = scal[2], inv_w = scal[3];
    ((float4*)bl)[t]        = ((const float4*)b)[t];
    ((float4*)bl)[1024 + t] = ((const float4*)b)[1024 + t];
    oh[t] = 0u; cur[t] = 0u;
    __syncthreads();
    int kb_[8];
    #pragma unroll
    for (int r = 0; r < 8; ++r) {
        kb_[r] = bucket_of(bl[t * 8 + r], bmin, inv_w);
        atomicAdd(&oh[kb_[r]], 1u);
    }
    __syncthreads();
    // inclusive scan of oh via shfl
    unsigned v = oh[t];
    #pragma unroll
    for (int d = 1; d < 64; d <<= 1) {
        unsigned u = __shfl_up(v, d);
        if (lane >= d) v += u;
    }
    if (lane == 63) wtu[wv] = v;
    __syncthreads();
    if (t < 16) {
        unsigned w = wtu[t];
        #pragma unroll
        for (int d = 1; d < 16; d <<= 1) {
            unsigned u = __shfl_up(w, d);
            if (t >= d) w += u;
        }
        wtu[t] = w;
    }
    __syncthreads();
    if (wv) v += wtu[wv - 1];
    oh[t] = v;
    __syncthreads();
    // scatter
    #pragma unroll
    for (int r = 0; r < 8; ++r) {
        int j = t * 8 + r;
        int k = kb_[r];
        unsigned e0 = k ? oh[k - 1] : 0u;
        unsigned pos = atomicAdd(&cur[k], 1u);
        ls[e0 + pos] = (unsigned short)j;
    }
    __syncthreads();
    if (c == 0) {
        #pragma unroll
        for (int r = 0; r < 8; ++r) list_g[r * 1024 + t] = (unsigned)ls[r * 1024 + t];
        offs_g[t + 1] = oh[t];
        if (t == 0) offs_g[0] = 0u;
    }
    // per-bucket sums for channel c (thread t = bucket t)
    unsigned e0 = t ? oh[t - 1] : 0u, e1 = oh[t];
    float h1 = 0.f, h2 = 0.f;
    for (unsigned e = e0; e < e1; ++e) {
        int j = ls[e];
        float bj = bl[j];
        float gv = (float)g[(size_t)j * C_INT + c];
        h1 += gv; h2 += bj * gv;
    }
    // inclusive scan of (h1,h2) via shfl
    float v1 = h1, v2 = h2;
    #pragma unroll
    for (int d = 1; d < 64; d <<= 1) {
        float u1 = __shfl_up(v1, d), u2 = __shfl_up(v2, d);
        if (lane >= d) { v1 += u1; v2 += u2; }
    }
    if (lane == 63) { wt1[wv] = v1; wt2[wv] = v2; }
    __syncthreads();
    if (t < 16) {
        float w1 = wt1[t], w2 = wt2[t];
        #pragma unroll
        for (int d = 1; d < 16; d <<= 1) {
            float u1 = __shfl_up(w1, d), u2 = __shfl_up(w2, d);
            if (t >= d) { w1 += u1; w2 += u2; }
        }
        wt1[t] = w1; wt2[t] = w2;
    }
    __syncthreads();
    if (wv) { v1 += wt1[wv - 1]; v2 += wt2[wv - 1]; }
    float tot1 = wt1[15], tot2 = wt2[15];
    P1[(size_t)t * C_INT + c] = tot1 - v1 + h1;   // sum over buckets >= t
    P2[(size_t)t * C_INT + c] = tot2 - v2 + h2;
    if (t == 0) {
        P1[(size_t)NBUCK * C_INT + c] = 0.f;
        P2[(size_t)NBUCK * C_INT + c] = 0.f;
    }
}

// ---------- K4: per-row output ----------

__global__ __launch_bounds__(128) void out_kernel(
        const float* __restrict__ a, const float* __restrict__ b,
        const _Float16* __restrict__ g, const float* __restrict__ scal,
        const unsigned* __restrict__ offs, const unsigned* __restrict__ list,
        const float* __restrict__ P1, const float* __restrict__ P2,
        float* __restrict__ out, int n, float inv_n) {
    int i = blockIdx.x, c = threadIdx.x;
    float ai = a[i], thr = -ai;
    float bmin = scal[2], inv_w = scal[3];
    int ki = bucket_of(thr, bmin, inv_w);
    size_t base = (size_t)(ki + 1) * C_INT;
    float acc = ai * P1[base + c] + P2[base + c];
    unsigned e0 = offs[ki], e1 = offs[ki + 1];
    for (unsigned e = e0; e < e1; ++e) {
        unsigned j = list[e];
        float bj = b[j];
        if (bj > thr) acc += (ai + bj) * (float)g[(size_t)j * C_INT + c];
    }
    out[(size_t)i * C_INT + c] = acc * inv_n;
}

// ---------- launch ----------

extern "C" void kernel_launch(void* const* d_in, const int* in_sizes, int n_in,
                              void* d_out, int out_size, void* d_ws, size_t ws_size,
                              hipStream_t stream) {
    const float* x    = (const float*)d_in[0];
    const float* Wg   = (const float*)d_in[1];
    const float* bg   = (const float*)d_in[2];
    const float* Wt   = (const float*)d_in[3];
    const float* bt   = (const float*)d_in[4];
    const float* Wp   = (const float*)d_in[5];
    const float* bp   = (const float*)d_in[6];
    const float* wcat = (const float*)d_in[7];
    float* out = (float*)d_out;
    int n = in_sizes[0] / C_IN;   // 8192

    char* w = (char*)d_ws;
    size_t off = 0;
    auto alloc = [&](size_t bytes) -> void* {
        void* p = w + off;
        off += (bytes + 255) & ~(size_t)255;
        return p;
    };
    float*          ut   = (float*)alloc(C_IN * 4);
    float*          up   = (float*)alloc(C_IN * 4);
    float*          scal = (float*)alloc(16);
    float*          a    = (float*)alloc((size_t)n * 4);
    float*          b    = (float*)alloc((size_t)n * 4);
    unsigned*       offs = (unsigned*)alloc((NBUCK + 1) * 4);
    unsigned*       list = (unsigned*)alloc((size_t)n * 4);
    _Float16*       g    = (_Float16*)alloc((size_t)n * C_INT * 2);
    unsigned short* WgT  = (unsigned short*)alloc((size_t)C_INT * C_IN * 2);
    float*          P1   = (float*)alloc((size_t)(NBUCK + 1) * C_INT * 4);
    float*          P2   = (float*)alloc((size_t)(NBUCK + 1) * C_INT * 4);

    prep_kernel<<<25, 256, 0, stream>>>(Wt, Wp, Wg, wcat, bt, bp, ut, up, scal, WgT);
    gemm_mfma<<<n / 16, 64, 0, stream>>>(x, WgT, bg, ut, up, scal, g, a, b);
    bucketsuffix_kernel<<<C_INT, 1024, 0, stream>>>(g, b, scal, offs, list, P1, P2, n);
    out_kernel<<<n, C_INT, 0, stream>>>(a, b, g, scal, offs, list, P1, P2,
                                        out, n, 1.0f / (float)n);
}

// Round 6
// 160.377 us; speedup vs baseline: 1.2324x; 1.0038x over previous
//
#include <hip/hip_runtime.h>

#define C_IN   512
#define C_INT  128
#define NBUCK  8192
#define SEG    32
#define NSEG   256   // NBUCK rows / SEG

typedef short short8 __attribute__((ext_vector_type(8)));
typedef float floatx4 __attribute__((ext_vector_type(4)));

// ---------- helpers ----------

// Monotone (after clamp) bucket mapping; identical everywhere it is used.
__device__ __forceinline__ int bucket_of(float v, float bmin, float inv_w) {
    float fk = (v - bmin) * inv_w;
    fk = fminf(fmaxf(fk, 0.f), (float)(NBUCK - 1));
    return (int)fk;
}

// fp32 -> bf16 round-to-nearest-even
__device__ __forceinline__ short bf16rnd(float v) {
    unsigned u = __float_as_uint(v);
    return (short)((u + 0x7fffu + ((u >> 16) & 1u)) >> 16);
}

// ---------- K1: prep ----------
// blocks 0..7: ut; 8..15: up; 16: scal = {s0, s1, bmin, inv_w}; 17..24: WgT.

__global__ __launch_bounds__(256) void prep_kernel(
        const float* __restrict__ Wt, const float* __restrict__ Wp,
        const float* __restrict__ Wg, const float* __restrict__ wcat,
        const float* __restrict__ bt, const float* __restrict__ bp,
        float* __restrict__ ut, float* __restrict__ up, float* __restrict__ scal,
        unsigned short* __restrict__ WgT) {
    int t = threadIdx.x, bk = blockIdx.x;
    if (bk < 16) {
        const float* W  = (bk < 8) ? Wt : Wp;
        const float* wv = wcat + ((bk < 8) ? 0 : C_INT);
        float* dst      = (bk < 8) ? ut : up;
        int k = (bk & 7) * 64 + (t >> 2);
        int q = t & 3;
        const float4* row = (const float4*)(W + (size_t)k * C_INT);
        const float4* cv4 = (const float4*)wv;
        float s = 0.f;
        #pragma unroll
        for (int i = 0; i < 8; ++i) {
            float4 a = row[q * 8 + i];
            float4 c = cv4[q * 8 + i];
            s += a.x * c.x + a.y * c.y + a.z * c.z + a.w * c.w;
        }
        s += __shfl_xor(s, 1);
        s += __shfl_xor(s, 2);
        if (q == 0) dst[k] = s;
    } else if (bk == 16) {
        float sumsq = 0.f;
        const float4* w2v = (const float4*)(wcat + C_INT);
        for (int r = 0; r < 2; ++r) {
            int k = t * 2 + r;
            const float4* row = (const float4*)(Wp + (size_t)k * C_INT);
            float d = 0.f;
            #pragma unroll
            for (int i = 0; i < 32; ++i) {
                float4 a4 = row[i]; float4 c4 = w2v[i];
                d += a4.x * c4.x + a4.y * c4.y + a4.z * c4.z + a4.w * c4.w;
            }
            sumsq += d * d;
        }
        float s1p = (t < C_INT) ? bt[t] * wcat[t] : 0.f;
        float s2p = (t < C_INT) ? bp[t] * wcat[C_INT + t] : 0.f;
        for (int off = 32; off; off >>= 1) {
            s1p   += __shfl_down(s1p, off);
            s2p   += __shfl_down(s2p, off);
            sumsq += __shfl_down(sumsq, off);
        }
        __shared__ float red[12];
        int w = t >> 6, lane = t & 63;
        if (lane == 0) { red[w] = s1p; red[4 + w] = s2p; red[8 + w] = sumsq; }
        __syncthreads();
        if (t == 0) {
            float s0 = red[0] + red[1] + red[2] + red[3];
            float s1 = red[4] + red[5] + red[6] + red[7];
            float sq = red[8] + red[9] + red[10] + red[11];
            float sigma = sqrtf(sq);
            scal[0] = s0; scal[1] = s1;
            if (sigma > 1e-20f) {
                scal[2] = s1 - 8.f * sigma;                  // bmin
                scal[3] = (float)NBUCK / (16.f * sigma);     // inv_w
            } else {
                scal[2] = s1 - 1.f; scal[3] = 0.f;           // degenerate
            }
        }
    } else {
        __shared__ float tile[64][132];
        int kb = (bk - 17) * 64;
        #pragma unroll
        for (int it = 0; it < 8; ++it) {
            int idx = it * 256 + t;
            int r = idx >> 5, c4 = idx & 31;
            *(float4*)&tile[r][c4 * 4] =
                ((const float4*)(Wg + (size_t)(kb + r) * C_INT))[c4];
        }
        __syncthreads();
        int n = t & 127, kc = (t >> 7) * 32;
        unsigned pk[16];
        #pragma unroll
        for (int i = 0; i < 16; ++i) {
            unsigned lo = (unsigned short)bf16rnd(tile[kc + 2 * i][n]);
            unsigned hi = (unsigned short)bf16rnd(tile[kc + 2 * i + 1][n]);
            pk[i] = lo | (hi << 16);
        }
        uint4* dst = (uint4*)(WgT + (size_t)n * C_IN + kb + kc);
        #pragma unroll
        for (int i2 = 0; i2 < 4; ++i2) dst[i2] = *(uint4*)&pk[i2 * 4];
    }
}

// ---------- K2: MFMA gemm (verified round 5, unchanged) ----------

__global__ __launch_bounds__(64) void gemm_mfma(
        const float* __restrict__ x, const unsigned short* __restrict__ WgT,
        const float* __restrict__ bg,
        const float* __restrict__ ut, const float* __restrict__ up,
        const float* __restrict__ scal,
        _Float16* __restrict__ g, float* __restrict__ a, float* __restrict__ b) {
    int lane = threadIdx.x;
    int i0 = blockIdx.x * 16;
    int m = lane & 15, q = lane >> 4;
    floatx4 accg[8] = {};
    floatx4 accab = {};
    const float* xrow = x + (size_t)(i0 + m) * C_IN + q * 8;
    const float* absrc = (m == 0) ? ut : up;
    #pragma unroll
    for (int ks = 0; ks < 16; ++ks) {
        int k0 = ks * 32;
        float4 f0 = *(const float4*)(xrow + k0);
        float4 f1 = *(const float4*)(xrow + k0 + 4);
        short8 af;
        af[0] = bf16rnd(f0.x); af[1] = bf16rnd(f0.y);
        af[2] = bf16rnd(f0.z); af[3] = bf16rnd(f0.w);
        af[4] = bf16rnd(f1.x); af[5] = bf16rnd(f1.y);
        af[6] = bf16rnd(f1.z); af[7] = bf16rnd(f1.w);
        short8 abf = {};
        if (m < 2) {
            float4 u0 = *(const float4*)(absrc + k0 + q * 8);
            float4 u1 = *(const float4*)(absrc + k0 + q * 8 + 4);
            abf[0] = bf16rnd(u0.x); abf[1] = bf16rnd(u0.y);
            abf[2] = bf16rnd(u0.z); abf[3] = bf16rnd(u0.w);
            abf[4] = bf16rnd(u1.x); abf[5] = bf16rnd(u1.y);
            abf[6] = bf16rnd(u1.z); abf[7] = bf16rnd(u1.w);
        }
        accab = __builtin_amdgcn_mfma_f32_16x16x32_bf16(af, abf, accab, 0, 0, 0);
        #pragma unroll
        for (int f = 0; f < 8; ++f) {
            short8 bfr = *(const short8*)(WgT + (size_t)(f * 16 + m) * C_IN + k0 + q * 8);
            accg[f] = __builtin_amdgcn_mfma_f32_16x16x32_bf16(af, bfr, accg[f], 0, 0, 0);
        }
    }
    #pragma unroll
    for (int f = 0; f < 8; ++f) {
        int col = f * 16 + m;
        float bgv = bg[col];
        #pragma unroll
        for (int r = 0; r < 4; ++r) {
            int row = i0 + q * 4 + r;
            g[(size_t)row * C_INT + col] = (_Float16)(accg[f][r] + bgv);
        }
    }
    if (m < 2) {
        float off = m ? scal[1] : scal[0];
        float* dst = m ? b : a;
        #pragma unroll
        for (int r = 0; r < 4; ++r) dst[i0 + q * 4 + r] = accab[r] + off;
    }
}

// ---------- K3: sort (single block): hist -> scan -> scatter; emits perm/bsort/offs ----------
// u16-pair-packed hist & cursors keep static LDS at ~48 KB.

__global__ __launch_bounds__(1024) void sort_kernel(
        const float* __restrict__ b, const float* __restrict__ scal,
        unsigned* __restrict__ offs_g, unsigned short* __restrict__ perm_g,
        float* __restrict__ bsort_g) {
    __shared__ unsigned oh[NBUCK / 2];    // packed u16 pairs: hist -> inclusive scan
    __shared__ unsigned cur[NBUCK / 2];   // packed u16 cursors
    __shared__ unsigned short ls[8192];
    __shared__ unsigned wtu[16];
    int t = threadIdx.x, lane = t & 63, wv = t >> 6;
    #pragma unroll
    for (int r = 0; r < 4; ++r) { oh[t + r * 1024] = 0u; cur[t + r * 1024] = 0u; }
    __syncthreads();
    float bmin = scal[2], inv_w = scal[3];
    int kb[8];
    float bv[8];
    #pragma unroll
    for (int r = 0; r < 8; ++r) {
        int j = t + r * 1024;
        bv[r] = b[j];
        kb[r] = bucket_of(bv[r], bmin, inv_w);
        atomicAdd(&oh[kb[r] >> 1], (kb[r] & 1) ? 0x10000u : 1u);
    }
    __syncthreads();
    // scan: thread t owns buckets t*8..t*8+7 (words t*4..t*4+3)
    unsigned h[8], p = 0;
    #pragma unroll
    for (int w = 0; w < 4; ++w) {
        unsigned word = oh[t * 4 + w];
        p += word & 0xffffu;  h[w * 2]     = p;
        p += word >> 16;      h[w * 2 + 1] = p;
    }
    unsigned v = p;
    #pragma unroll
    for (int d = 1; d < 64; d <<= 1) {
        unsigned u = __shfl_up(v, d);
        if (lane >= d) v += u;
    }
    if (lane == 63) wtu[wv] = v;
    __syncthreads();
    if (t < 16) {
        unsigned w = wtu[t];
        #pragma unroll
        for (int d = 1; d < 16; d <<= 1) {
            unsigned u = __shfl_up(w, d);
            if (t >= d) w += u;
        }
        wtu[t] = w;
    }
    __syncthreads();
    unsigned base = (v - p) + (wv ? wtu[wv - 1] : 0u);
    #pragma unroll
    for (int w = 0; w < 4; ++w) {
        unsigned lo = base + h[w * 2], hi = base + h[w * 2 + 1];
        oh[t * 4 + w] = lo | (hi << 16);             // inclusive, packed
        offs_g[t * 8 + w * 2 + 1] = lo;
        offs_g[t * 8 + w * 2 + 2] = hi;
    }
    if (t == 0) offs_g[0] = 0u;
    __syncthreads();
    // scatter
    #pragma unroll
    for (int r = 0; r < 8; ++r) {
        int j = t + r * 1024;
        int k = kb[r];
        unsigned st = 0u;
        if (k > 0) {
            unsigned word = oh[(k - 1) >> 1];
            st = ((k - 1) & 1) ? (word >> 16) : (word & 0xffffu);
        }
        unsigned old = atomicAdd(&cur[k >> 1], (k & 1) ? 0x10000u : 1u);
        unsigned pos = (k & 1) ? (old >> 16) : (old & 0xffffu);
        ls[st + pos] = (unsigned short)j;
    }
    __syncthreads();
    // write perm + bsort (gather b from global; L2-hot)
    #pragma unroll
    for (int r = 0; r < 8; ++r) {
        int e = t + r * 1024;
        int j = ls[e];
        perm_g[e] = (unsigned short)j;
        bsort_g[e] = b[j];
    }
}

// ---------- K4: per-segment sums (SEG sorted rows x 128 channels per block) ----------

__global__ __launch_bounds__(128) void segsum_kernel(
        const _Float16* __restrict__ g, const unsigned short* __restrict__ perm,
        const float* __restrict__ bsort,
        float* __restrict__ seg1, float* __restrict__ seg2) {
    __shared__ int pj[SEG];
    __shared__ float pb[SEG];
    int s = blockIdx.x, t = threadIdx.x;
    if (t < SEG) { pj[t] = perm[s * SEG + t]; pb[t] = bsort[s * SEG + t]; }
    __syncthreads();
    float a1 = 0.f, a2 = 0.f;
    #pragma unroll
    for (int e = 0; e < SEG; ++e) {
        float gv = (float)g[(size_t)pj[e] * C_INT + t];
        a1 += gv; a2 += pb[e] * gv;
    }
    seg1[s * C_INT + t] = a1;
    seg2[s * C_INT + t] = a2;
}

// ---------- K5: expand to row-granular suffix sums Pr1/Pr2 [8193][128] ----------
// Each block redundantly computes its suffix-of-segments start (coalesced,
// independent loads), then walks its SEG rows downward writing Pr.

__global__ __launch_bounds__(128) void expand_kernel(
        const _Float16* __restrict__ g, const unsigned short* __restrict__ perm,
        const float* __restrict__ bsort,
        const float* __restrict__ seg1, const float* __restrict__ seg2,
        float* __restrict__ Pr1, float* __restrict__ Pr2) {
    __shared__ int pj[SEG];
    __shared__ float pb[SEG];
    int s = blockIdx.x, t = threadIdx.x;
    if (t < SEG) { pj[t] = perm[s * SEG + t]; pb[t] = bsort[s * SEG + t]; }
    __syncthreads();
    float r1 = 0.f, r2 = 0.f;
    for (int s2 = s + 1; s2 < NSEG; ++s2) {
        r1 += seg1[s2 * C_INT + t];
        r2 += seg2[s2 * C_INT + t];
    }
    #pragma unroll
    for (int e = SEG - 1; e >= 0; --e) {
        float gv = (float)g[(size_t)pj[e] * C_INT + t];
        r1 += gv; r2 += pb[e] * gv;
        size_t idx = (size_t)(s * SEG + e) * C_INT + t;
        Pr1[idx] = r1; Pr2[idx] = r2;
    }
    if (s == NSEG - 1) {
        Pr1[(size_t)8192 * C_INT + t] = 0.f;
        Pr2[(size_t)8192 * C_INT + t] = 0.f;
    }
}

// ---------- K6: per-row output: suffix lookup + tiny exact tail ----------

__global__ __launch_bounds__(128) void out_kernel(
        const float* __restrict__ a, const float* __restrict__ scal,
        const _Float16* __restrict__ g,
        const unsigned* __restrict__ offs, const unsigned short* __restrict__ perm,
        const float* __restrict__ bsort,
        const float* __restrict__ Pr1, const float* __restrict__ Pr2,
        float* __restrict__ out, float inv_n) {
    __shared__ int pj[128];
    __shared__ float pb[128];
    int i = blockIdx.x, c = threadIdx.x;
    float ai = a[i], thr = -ai;
    float bmin = scal[2], inv_w = scal[3];
    int ki = bucket_of(thr, bmin, inv_w);
    unsigned e0 = offs[ki], e1 = offs[ki + 1];
    size_t base = (size_t)e1 * C_INT + c;
    float acc = ai * Pr1[base] + Pr2[base];
    for (unsigned be = e0; be < e1; be += 128) {
        unsigned cnt = min(128u, e1 - be);
        if ((unsigned)c < cnt) { pj[c] = perm[be + c]; pb[c] = bsort[be + c]; }
        __syncthreads();
        for (unsigned r = 0; r < cnt; ++r) {
            float bj = pb[r];
            if (bj > thr)
                acc += (ai + bj) * (float)g[(size_t)pj[r] * C_INT + c];
        }
        __syncthreads();
    }
    out[(size_t)i * C_INT + c] = acc * inv_n;
}

// ---------- launch ----------

extern "C" void kernel_launch(void* const* d_in, const int* in_sizes, int n_in,
                              void* d_out, int out_size, void* d_ws, size_t ws_size,
                              hipStream_t stream) {
    const float* x    = (const float*)d_in[0];
    const float* Wg   = (const float*)d_in[1];
    const float* bg   = (const float*)d_in[2];
    const float* Wt   = (const float*)d_in[3];
    const float* bt   = (const float*)d_in[4];
    const float* Wp   = (const float*)d_in[5];
    const float* bp   = (const float*)d_in[6];
    const float* wcat = (const float*)d_in[7];
    float* out = (float*)d_out;
    int n = in_sizes[0] / C_IN;   // 8192

    char* w = (char*)d_ws;
    size_t off = 0;
    auto alloc = [&](size_t bytes) -> void* {
        void* p = w + off;
        off += (bytes + 255) & ~(size_t)255;
        return p;
    };
    float*          ut    = (float*)alloc(C_IN * 4);
    float*          up    = (float*)alloc(C_IN * 4);
    float*          scal  = (float*)alloc(16);
    float*          a     = (float*)alloc((size_t)n * 4);
    float*          b     = (float*)alloc((size_t)n * 4);
    unsigned*       offs  = (unsigned*)alloc((size_t)(NBUCK + 1) * 4);
    unsigned short* perm  = (unsigned short*)alloc((size_t)n * 2);
    float*          bsort = (float*)alloc((size_t)n * 4);
    _Float16*       g     = (_Float16*)alloc((size_t)n * C_INT * 2);
    unsigned short* WgT   = (unsigned short*)alloc((size_t)C_INT * C_IN * 2);
    float*          seg1  = (float*)alloc((size_t)NSEG * C_INT * 4);
    float*          seg2  = (float*)alloc((size_t)NSEG * C_INT * 4);
    float*          Pr1   = (float*)alloc((size_t)(n + 1) * C_INT * 4);
    float*          Pr2   = (float*)alloc((size_t)(n + 1) * C_INT * 4);

    prep_kernel<<<25, 256, 0, stream>>>(Wt, Wp, Wg, wcat, bt, bp, ut, up, scal, WgT);
    gemm_mfma<<<n / 16, 64, 0, stream>>>(x, WgT, bg, ut, up, scal, g, a, b);
    sort_kernel<<<1, 1024, 0, stream>>>(b, scal, offs, perm, bsort);
    segsum_kernel<<<NSEG, 128, 0, stream>>>(g, perm, bsort, seg1, seg2);
    expand_kernel<<<NSEG, 128, 0, stream>>>(g, perm, bsort, seg1, seg2, Pr1, Pr2);
    out_kernel<<<n, 128, 0, stream>>>(a, scal, g, offs, perm, bsort, Pr1, Pr2,
                                      out, 1.0f / (float)n);
}

// Round 7
// 151.809 us; speedup vs baseline: 1.3019x; 1.0564x over previous
//
#include <hip/hip_runtime.h>

#define C_IN   512
#define C_INT  128
#define NBUCK  8192
#define SEG    32
#define NSEG   256   // 8192 / SEG

typedef short short8 __attribute__((ext_vector_type(8)));
typedef float floatx4 __attribute__((ext_vector_type(4)));

// ---------- helpers ----------

// Monotone (after clamp) bucket mapping; identical everywhere it is used.
__device__ __forceinline__ int bucket_of(float v, float bmin, float inv_w) {
    float fk = (v - bmin) * inv_w;
    fk = fminf(fmaxf(fk, 0.f), (float)(NBUCK - 1));
    return (int)fk;
}

// fp32 -> bf16 round-to-nearest-even
__device__ __forceinline__ short bf16rnd(float v) {
    unsigned u = __float_as_uint(v);
    return (short)((u + 0x7fffu + ((u >> 16) & 1u)) >> 16);
}

// ---------- K1: prep (verified r5) ----------
// blocks 0..7: ut; 8..15: up; 16: scal = {s0, s1, bmin, inv_w}; 17..24: WgT.

__global__ __launch_bounds__(256) void prep_kernel(
        const float* __restrict__ Wt, const float* __restrict__ Wp,
        const float* __restrict__ Wg, const float* __restrict__ wcat,
        const float* __restrict__ bt, const float* __restrict__ bp,
        float* __restrict__ ut, float* __restrict__ up, float* __restrict__ scal,
        unsigned short* __restrict__ WgT) {
    int t = threadIdx.x, bk = blockIdx.x;
    if (bk < 16) {
        const float* W  = (bk < 8) ? Wt : Wp;
        const float* wv = wcat + ((bk < 8) ? 0 : C_INT);
        float* dst      = (bk < 8) ? ut : up;
        int k = (bk & 7) * 64 + (t >> 2);
        int q = t & 3;
        const float4* row = (const float4*)(W + (size_t)k * C_INT);
        const float4* cv4 = (const float4*)wv;
        float s = 0.f;
        #pragma unroll
        for (int i = 0; i < 8; ++i) {
            float4 a = row[q * 8 + i];
            float4 c = cv4[q * 8 + i];
            s += a.x * c.x + a.y * c.y + a.z * c.z + a.w * c.w;
        }
        s += __shfl_xor(s, 1);
        s += __shfl_xor(s, 2);
        if (q == 0) dst[k] = s;
    } else if (bk == 16) {
        float sumsq = 0.f;
        const float4* w2v = (const float4*)(wcat + C_INT);
        for (int r = 0; r < 2; ++r) {
            int k = t * 2 + r;
            const float4* row = (const float4*)(Wp + (size_t)k * C_INT);
            float d = 0.f;
            #pragma unroll
            for (int i = 0; i < 32; ++i) {
                float4 a4 = row[i]; float4 c4 = w2v[i];
                d += a4.x * c4.x + a4.y * c4.y + a4.z * c4.z + a4.w * c4.w;
            }
            sumsq += d * d;
        }
        float s1p = (t < C_INT) ? bt[t] * wcat[t] : 0.f;
        float s2p = (t < C_INT) ? bp[t] * wcat[C_INT + t] : 0.f;
        for (int off = 32; off; off >>= 1) {
            s1p   += __shfl_down(s1p, off);
            s2p   += __shfl_down(s2p, off);
            sumsq += __shfl_down(sumsq, off);
        }
        __shared__ float red[12];
        int w = t >> 6, lane = t & 63;
        if (lane == 0) { red[w] = s1p; red[4 + w] = s2p; red[8 + w] = sumsq; }
        __syncthreads();
        if (t == 0) {
            float s0 = red[0] + red[1] + red[2] + red[3];
            float s1 = red[4] + red[5] + red[6] + red[7];
            float sq = red[8] + red[9] + red[10] + red[11];
            float sigma = sqrtf(sq);
            scal[0] = s0; scal[1] = s1;
            if (sigma > 1e-20f) {
                scal[2] = s1 - 8.f * sigma;                  // bmin
                scal[3] = (float)NBUCK / (16.f * sigma);     // inv_w
            } else {
                scal[2] = s1 - 1.f; scal[3] = 0.f;           // degenerate
            }
        }
    } else {
        __shared__ float tile[64][132];
        int kb = (bk - 17) * 64;
        #pragma unroll
        for (int it = 0; it < 8; ++it) {
            int idx = it * 256 + t;
            int r = idx >> 5, c4 = idx & 31;
            *(float4*)&tile[r][c4 * 4] =
                ((const float4*)(Wg + (size_t)(kb + r) * C_INT))[c4];
        }
        __syncthreads();
        int n = t & 127, kc = (t >> 7) * 32;
        unsigned pk[16];
        #pragma unroll
        for (int i = 0; i < 16; ++i) {
            unsigned lo = (unsigned short)bf16rnd(tile[kc + 2 * i][n]);
            unsigned hi = (unsigned short)bf16rnd(tile[kc + 2 * i + 1][n]);
            pk[i] = lo | (hi << 16);
        }
        uint4* dst = (uint4*)(WgT + (size_t)n * C_IN + kb + kc);
        #pragma unroll
        for (int i2 = 0; i2 < 4; ++i2) dst[i2] = *(uint4*)&pk[i2 * 4];
    }
}

// ---------- K2: MFMA gemm, 4 waves/block K-split (8 waves/CU) ----------
// Each wave: 16 rows x 128 cols over its K-quarter (K=128). LDS reduce
// (stride-66 b32 rows: 2-way bank aliasing = free). Wave 0 epilogue.

#define RSTR 66   // LDS reduce row stride (floats): 2*lane mod 32 -> 2-way, free

__global__ __launch_bounds__(256) void gemm_mfma(
        const float* __restrict__ x, const unsigned short* __restrict__ WgT,
        const float* __restrict__ bg,
        const float* __restrict__ ut, const float* __restrict__ up,
        const float* __restrict__ scal,
        _Float16* __restrict__ g, float* __restrict__ a, float* __restrict__ b) {
    __shared__ float red[3][36][RSTR];
    int tid = threadIdx.x;
    int lane = tid & 63, wv = tid >> 6;
    int i0 = blockIdx.x * 16;
    int m = lane & 15, q = lane >> 4;
    floatx4 accg[8] = {};
    floatx4 accab = {};
    const float* xrow = x + (size_t)(i0 + m) * C_IN + q * 8;
    const float* absrc = (m == 0) ? ut : up;
    #pragma unroll
    for (int ks = 0; ks < 4; ++ks) {
        int k0 = (wv * 4 + ks) * 32;
        float4 f0 = *(const float4*)(xrow + k0);
        float4 f1 = *(const float4*)(xrow + k0 + 4);
        short8 af;
        af[0] = bf16rnd(f0.x); af[1] = bf16rnd(f0.y);
        af[2] = bf16rnd(f0.z); af[3] = bf16rnd(f0.w);
        af[4] = bf16rnd(f1.x); af[5] = bf16rnd(f1.y);
        af[6] = bf16rnd(f1.z); af[7] = bf16rnd(f1.w);
        short8 abf = {};
        if (m < 2) {
            float4 u0 = *(const float4*)(absrc + k0 + q * 8);
            float4 u1 = *(const float4*)(absrc + k0 + q * 8 + 4);
            abf[0] = bf16rnd(u0.x); abf[1] = bf16rnd(u0.y);
            abf[2] = bf16rnd(u0.z); abf[3] = bf16rnd(u0.w);
            abf[4] = bf16rnd(u1.x); abf[5] = bf16rnd(u1.y);
            abf[6] = bf16rnd(u1.z); abf[7] = bf16rnd(u1.w);
        }
        accab = __builtin_amdgcn_mfma_f32_16x16x32_bf16(af, abf, accab, 0, 0, 0);
        #pragma unroll
        for (int f = 0; f < 8; ++f) {
            short8 bfr = *(const short8*)(WgT + (size_t)(f * 16 + m) * C_IN + k0 + q * 8);
            accg[f] = __builtin_amdgcn_mfma_f32_16x16x32_bf16(af, bfr, accg[f], 0, 0, 0);
        }
    }
    if (wv) {
        #pragma unroll
        for (int f = 0; f < 8; ++f)
            #pragma unroll
            for (int r = 0; r < 4; ++r)
                red[wv - 1][f * 4 + r][lane] = accg[f][r];
        #pragma unroll
        for (int r = 0; r < 4; ++r)
            red[wv - 1][32 + r][lane] = accab[r];
    }
    __syncthreads();
    if (wv == 0) {
        #pragma unroll
        for (int w = 0; w < 3; ++w) {
            #pragma unroll
            for (int f = 0; f < 8; ++f)
                #pragma unroll
                for (int r = 0; r < 4; ++r)
                    accg[f][r] += red[w][f * 4 + r][lane];
            #pragma unroll
            for (int r = 0; r < 4; ++r)
                accab[r] += red[w][32 + r][lane];
        }
        // epilogue: C layout col = lane&15, row = q*4 + reg
        #pragma unroll
        for (int f = 0; f < 8; ++f) {
            int col = f * 16 + m;
            float bgv = bg[col];
            #pragma unroll
            for (int r = 0; r < 4; ++r) {
                int row = i0 + q * 4 + r;
                g[(size_t)row * C_INT + col] = (_Float16)(accg[f][r] + bgv);
            }
        }
        if (m < 2) {
            float off = m ? scal[1] : scal[0];
            float* dst = m ? b : a;
            #pragma unroll
            for (int r = 0; r < 4; ++r) dst[i0 + q * 4 + r] = accab[r] + off;
        }
    }
}

// ---------- K3: sort (single block, verified r6) ----------

__global__ __launch_bounds__(1024) void sort_kernel(
        const float* __restrict__ b, const float* __restrict__ scal,
        unsigned* __restrict__ offs_g, unsigned short* __restrict__ perm_g,
        float* __restrict__ bsort_g) {
    __shared__ unsigned oh[NBUCK / 2];
    __shared__ unsigned cur[NBUCK / 2];
    __shared__ unsigned short ls[8192];
    __shared__ unsigned wtu[16];
    int t = threadIdx.x, lane = t & 63, wv = t >> 6;
    #pragma unroll
    for (int r = 0; r < 4; ++r) { oh[t + r * 1024] = 0u; cur[t + r * 1024] = 0u; }
    __syncthreads();
    float bmin = scal[2], inv_w = scal[3];
    int kb[8];
    #pragma unroll
    for (int r = 0; r < 8; ++r) {
        int j = t + r * 1024;
        kb[r] = bucket_of(b[j], bmin, inv_w);
        atomicAdd(&oh[kb[r] >> 1], (kb[r] & 1) ? 0x10000u : 1u);
    }
    __syncthreads();
    unsigned h[8], p = 0;
    #pragma unroll
    for (int w = 0; w < 4; ++w) {
        unsigned word = oh[t * 4 + w];
        p += word & 0xffffu;  h[w * 2]     = p;
        p += word >> 16;      h[w * 2 + 1] = p;
    }
    unsigned v = p;
    #pragma unroll
    for (int d = 1; d < 64; d <<= 1) {
        unsigned u = __shfl_up(v, d);
        if (lane >= d) v += u;
    }
    if (lane == 63) wtu[wv] = v;
    __syncthreads();
    if (t < 16) {
        unsigned w = wtu[t];
        #pragma unroll
        for (int d = 1; d < 16; d <<= 1) {
            unsigned u = __shfl_up(w, d);
            if (t >= d) w += u;
        }
        wtu[t] = w;
    }
    __syncthreads();
    unsigned base = (v - p) + (wv ? wtu[wv - 1] : 0u);
    #pragma unroll
    for (int w = 0; w < 4; ++w) {
        unsigned lo = base + h[w * 2], hi = base + h[w * 2 + 1];
        oh[t * 4 + w] = lo | (hi << 16);
        offs_g[t * 8 + w * 2 + 1] = lo;
        offs_g[t * 8 + w * 2 + 2] = hi;
    }
    if (t == 0) offs_g[0] = 0u;
    __syncthreads();
    #pragma unroll
    for (int r = 0; r < 8; ++r) {
        int j = t + r * 1024;
        int k = kb[r];
        unsigned st = 0u;
        if (k > 0) {
            unsigned word = oh[(k - 1) >> 1];
            st = ((k - 1) & 1) ? (word >> 16) : (word & 0xffffu);
        }
        unsigned old = atomicAdd(&cur[k >> 1], (k & 1) ? 0x10000u : 1u);
        unsigned pos = (k & 1) ? (old >> 16) : (old & 0xffffu);
        ls[st + pos] = (unsigned short)j;
    }
    __syncthreads();
    #pragma unroll
    for (int r = 0; r < 8; ++r) {
        int e = t + r * 1024;
        int j = ls[e];
        perm_g[e] = (unsigned short)j;
        bsort_g[e] = b[j];
    }
}

// ---------- K4: per-segment sums ----------

__global__ __launch_bounds__(128) void segsum_kernel(
        const _Float16* __restrict__ g, const unsigned short* __restrict__ perm,
        const float* __restrict__ bsort,
        float* __restrict__ seg1, float* __restrict__ seg2) {
    __shared__ int pj[SEG];
    __shared__ float pb[SEG];
    int s = blockIdx.x, t = threadIdx.x;
    if (t < SEG) { pj[t] = perm[s * SEG + t]; pb[t] = bsort[s * SEG + t]; }
    __syncthreads();
    float a1 = 0.f, a2 = 0.f;
    #pragma unroll
    for (int e = 0; e < SEG; ++e) {
        float gv = (float)g[(size_t)pj[e] * C_INT + t];
        a1 += gv; a2 += pb[e] * gv;
    }
    seg1[s * C_INT + t] = a1;
    seg2[s * C_INT + t] = a2;
}

// ---------- K5: expand to row-granular suffix sums Pr1/Pr2 ----------

__global__ __launch_bounds__(128) void expand_kernel(
        const _Float16* __restrict__ g, const unsigned short* __restrict__ perm,
        const float* __restrict__ bsort,
        const float* __restrict__ seg1, const float* __restrict__ seg2,
        float* __restrict__ Pr1, float* __restrict__ Pr2) {
    __shared__ int pj[SEG];
    __shared__ float pb[SEG];
    int s = blockIdx.x, t = threadIdx.x;
    if (t < SEG) { pj[t] = perm[s * SEG + t]; pb[t] = bsort[s * SEG + t]; }
    __syncthreads();
    float r1 = 0.f, r2 = 0.f;
    for (int s2 = s + 1; s2 < NSEG; ++s2) {
        r1 += seg1[s2 * C_INT + t];
        r2 += seg2[s2 * C_INT + t];
    }
    #pragma unroll
    for (int e = SEG - 1; e >= 0; --e) {
        float gv = (float)g[(size_t)pj[e] * C_INT + t];
        r1 += gv; r2 += pb[e] * gv;
        size_t idx = (size_t)(s * SEG + e) * C_INT + t;
        Pr1[idx] = r1; Pr2[idx] = r2;
    }
    if (s == NSEG - 1) {
        Pr1[(size_t)8192 * C_INT + t] = 0.f;
        Pr2[(size_t)8192 * C_INT + t] = 0.f;
    }
}

// ---------- K6: per-row output ----------

__global__ __launch_bounds__(128) void out_kernel(
        const float* __restrict__ a, const float* __restrict__ scal,
        const _Float16* __restrict__ g,
        const unsigned* __restrict__ offs, const unsigned short* __restrict__ perm,
        const float* __restrict__ bsort,
        const float* __restrict__ Pr1, const float* __restrict__ Pr2,
        float* __restrict__ out, float inv_n) {
    __shared__ int pj[128];
    __shared__ float pb[128];
    int i = blockIdx.x, c = threadIdx.x;
    float ai = a[i], thr = -ai;
    float bmin = scal[2], inv_w = scal[3];
    int ki = bucket_of(thr, bmin, inv_w);
    unsigned e0 = offs[ki], e1 = offs[ki + 1];
    size_t base = (size_t)e1 * C_INT + c;
    float acc = ai * Pr1[base] + Pr2[base];
    for (unsigned be = e0; be < e1; be += 128) {
        unsigned cnt = min(128u, e1 - be);
        if ((unsigned)c < cnt) { pj[c] = perm[be + c]; pb[c] = bsort[be + c]; }
        __syncthreads();
        for (unsigned r = 0; r < cnt; ++r) {
            float bj = pb[r];
            if (bj > thr)
                acc += (ai + bj) * (float)g[(size_t)pj[r] * C_INT + c];
        }
        __syncthreads();
    }
    out[(size_t)i * C_INT + c] = acc * inv_n;
}

// ---------- launch ----------

extern "C" void kernel_launch(void* const* d_in, const int* in_sizes, int n_in,
                              void* d_out, int out_size, void* d_ws, size_t ws_size,
                              hipStream_t stream) {
    const float* x    = (const float*)d_in[0];
    const float* Wg   = (const float*)d_in[1];
    const float* bg   = (const float*)d_in[2];
    const float* Wt   = (const float*)d_in[3];
    const float* bt   = (const float*)d_in[4];
    const float* Wp   = (const float*)d_in[5];
    const float* bp   = (const float*)d_in[6];
    const float* wcat = (const float*)d_in[7];
    float* out = (float*)d_out;
    int n = in_sizes[0] / C_IN;   // 8192

    char* w = (char*)d_ws;
    size_t off = 0;
    auto alloc = [&](size_t bytes) -> void* {
        void* p = w + off;
        off += (bytes + 255) & ~(size_t)255;
        return p;
    };
    float*          ut    = (float*)alloc(C_IN * 4);
    float*          up    = (float*)alloc(C_IN * 4);
    float*          scal  = (float*)alloc(16);
    float*          a     = (float*)alloc((size_t)n * 4);
    float*          b     = (float*)alloc((size_t)n * 4);
    unsigned*       offs  = (unsigned*)alloc((size_t)(NBUCK + 1) * 4);
    unsigned short* perm  = (unsigned short*)alloc((size_t)n * 2);
    float*          bsort = (float*)alloc((size_t)n * 4);
    _Float16*       g     = (_Float16*)alloc((size_t)n * C_INT * 2);
    unsigned short* WgT   = (unsigned short*)alloc((size_t)C_INT * C_IN * 2);
    float*          seg1  = (float*)alloc((size_t)NSEG * C_INT * 4);
    float*          seg2  = (float*)alloc((size_t)NSEG * C_INT * 4);
    float*          Pr1   = (float*)alloc((size_t)(n + 1) * C_INT * 4);
    float*          Pr2   = (float*)alloc((size_t)(n + 1) * C_INT * 4);

    prep_kernel<<<25, 256, 0, stream>>>(Wt, Wp, Wg, wcat, bt, bp, ut, up, scal, WgT);
    gemm_mfma<<<n / 16, 256, 0, stream>>>(x, WgT, bg, ut, up, scal, g, a, b);
    sort_kernel<<<1, 1024, 0, stream>>>(b, scal, offs, perm, bsort);
    segsum_kernel<<<NSEG, 128, 0, stream>>>(g, perm, bsort, seg1, seg2);
    expand_kernel<<<NSEG, 128, 0, stream>>>(g, perm, bsort, seg1, seg2, Pr1, Pr2);
    out_kernel<<<n, 128, 0, stream>>>(a, scal, g, offs, perm, bsort, Pr1, Pr2,
                                      out, 1.0f / (float)n);
}